// Round 9
// baseline (492.438 us; speedup 1.0000x reference)
//
#include <hip/hip_runtime.h>
#include <hip/hip_bf16.h>
#include <stdint.h>

#define N_SAM 10000
#define N_GEN 20000
#define DSAM  2000
#define DGEN  500
#define NB    32      // counting-sort chunks (round-7 proven)
#define NBNS  10240   // max LDS bins per hist slice (40 KB)
#define SSPAN 2560    // scatter slice span (10 KB LDS, 12 slices -> 384 blocks)
#define MP_SAM 10048  // 157*64 padded rows
#define MP_GEN 20032  // 313*64 padded rows

typedef __hip_bfloat16 bf16;
typedef short bf16x8 __attribute__((ext_vector_type(8)));
typedef float f32x4 __attribute__((ext_vector_type(4)));
typedef float f32x2 __attribute__((ext_vector_type(2)));

__device__ __forceinline__ float bfbits2f(unsigned short u) {
    unsigned v = ((unsigned)u) << 16;
    return __builtin_bit_cast(float, v);
}
__device__ __forceinline__ unsigned short f2bfbits(float f) {
    bf16 h = __float2bfloat16(f);
    return __builtin_bit_cast(unsigned short, h);
}
__device__ __forceinline__ unsigned packbf2(float lo, float hi) {
    return ((unsigned)f2bfbits(lo)) | (((unsigned)f2bfbits(hi)) << 16);
}
// unpack one dword (2 bf16) -> float2
__device__ __forceinline__ f32x2 b2f2(unsigned x) {
    f32x2 r;
    r.x = __builtin_bit_cast(float, x << 16);
    r.y = __builtin_bit_cast(float, x & 0xffff0000u);
    return r;
}
__device__ __forceinline__ void addu2(uint4 u, f32x2* a) {
    a[0] += b2f2(u.x);
    a[1] += b2f2(u.y);
    a[2] += b2f2(u.z);
    a[3] += b2f2(u.w);
}
// async global->LDS 16B (dwordx4). LDS dest must be linear in lane order.
__device__ __forceinline__ void gload16(const unsigned short* g, unsigned short* l) {
    __builtin_amdgcn_global_load_lds(
        (const __attribute__((address_space(1))) void*)g,
        (__attribute__((address_space(3))) void*)l, 16, 0, 0);
}

// ---------------------------------------------------------------------------
// Counting-sort phase 1: per-(block,bin) histograms, LDS-privatized.
// ---------------------------------------------------------------------------
__global__ __launch_bounds__(1024) void hist_count_kernel(
    const int* __restrict__ ssg, const int* __restrict__ dsg,
    const int* __restrict__ sgs, const int* __restrict__ dgs,
    unsigned* __restrict__ cs_ssg, unsigned* __restrict__ cs_dsg,
    unsigned* __restrict__ cs_sgs, unsigned* __restrict__ cs_dgs,
    int ne, int chunk) {
    __shared__ unsigned bins[NBNS];
    const int* arr; unsigned* counts; int lo, hi, nb;
    switch (blockIdx.y) {
        case 0:  arr = ssg; counts = cs_ssg; lo = 0;     hi = 10000; nb = 10000; break;
        case 1:  arr = dsg; counts = cs_dsg; lo = 0;     hi = 10240; nb = 20000; break;
        case 2:  arr = dsg; counts = cs_dsg; lo = 10240; hi = 20000; nb = 20000; break;
        case 3:  arr = sgs; counts = cs_sgs; lo = 0;     hi = 10240; nb = 20000; break;
        case 4:  arr = sgs; counts = cs_sgs; lo = 10240; hi = 20000; nb = 20000; break;
        default: arr = dgs; counts = cs_dgs; lo = 0;     hi = 10000; nb = 10000; break;
    }
    int span = hi - lo;
    for (int i = threadIdx.x; i < span; i += 1024) bins[i] = 0u;
    __syncthreads();
    int blk = blockIdx.x;
    int e0 = blk * chunk;
    int e1 = e0 + chunk; if (e1 > ne) e1 = ne;
    for (int e = e0 + threadIdx.x; e < e1; e += 1024) {
        int b = arr[e];
        if (b >= lo && b < hi) atomicAdd(&bins[b - lo], 1u);
    }
    __syncthreads();
    unsigned* out = counts + (size_t)blk * nb + lo;
    for (int i = threadIdx.x; i < span; i += 1024) out[i] = bins[i];
}

// ---------------------------------------------------------------------------
// Reduce per-block counts -> totals; fused degree normalizers rsqrt(max(d,1)).
// ---------------------------------------------------------------------------
__global__ __launch_bounds__(256) void reduce_counts_kernel(
    const unsigned* __restrict__ cs_ssg, const unsigned* __restrict__ cs_dsg,
    const unsigned* __restrict__ cs_sgs, const unsigned* __restrict__ cs_dgs,
    unsigned* __restrict__ cnt_dsg, unsigned* __restrict__ cnt_dgs,
    float* __restrict__ rs_out_sam, float* __restrict__ rs_in_gen,
    float* __restrict__ rs_out_gen, float* __restrict__ rs_in_sam) {
    int i = blockIdx.x * 256 + threadIdx.x;
    int which = blockIdx.y;
    const unsigned* cs; int nb;
    switch (which) {
        case 0:  cs = cs_ssg; nb = 10000; break;
        case 1:  cs = cs_dsg; nb = 20000; break;
        case 2:  cs = cs_sgs; nb = 20000; break;
        default: cs = cs_dgs; nb = 10000; break;
    }
    if (i >= nb) return;
    unsigned s = 0;
    #pragma unroll 4
    for (int b = 0; b < NB; b++) s += cs[(size_t)b * nb + i];
    unsigned c = (s < 1u) ? 1u : s;
    float r = rsqrtf((float)c);
    if (which == 0)      { rs_out_sam[i] = r; }
    else if (which == 1) { cnt_dsg[i] = s; rs_in_gen[i] = r; }
    else if (which == 2) { rs_out_gen[i] = r; }
    else                 { cnt_dgs[i] = s; rs_in_sam[i] = r; }
}

// ---------------------------------------------------------------------------
// Weight transpose descriptor (used inside fused scan/conv kernel)
// ---------------------------------------------------------------------------
struct WDesc { const float* src; unsigned short* dst; int K, N, Kp; };

// ---------------------------------------------------------------------------
// Fused: two exclusive scans (blocks 0,1) + fp32->bf16 feature conversion +
// hs/hg pad zeroing + weight transpose (all independent of the scans).
// ---------------------------------------------------------------------------
struct ScanConvArgs {
    const unsigned* c0; unsigned* r0; int nA;
    const unsigned* c1; unsigned* r1; int nB;
    const float* fsrcA; unsigned short* fdstA;   // sam feats
    const float* fsrcB; unsigned short* fdstB;   // gen feats
    unsigned short* z0; int nz0; unsigned short* z1; int nz1;
    int nConvA, nConvB;  // block counts for the two convert ranges
    WDesc wd[8];
    int twOff[8];        // per-desc block prefix offsets
    int nTW;
};

__device__ __forceinline__ void conv_body(
    const float* __restrict__ src, unsigned short* __restrict__ dst,
    int M, int K, int Mp, int kshift, int cb, int ncb) {
    const int Kp = 1 << kshift;
    size_t ng = ((size_t)Mp << kshift) >> 3;  // groups of 8 elements
    for (size_t gi = (size_t)cb * 1024 + threadIdx.x; gi < ng;
         gi += (size_t)ncb * 1024) {
        size_t o8 = gi << 3;
        int row = (int)(o8 >> kshift);
        int col = (int)(o8 & (size_t)(Kp - 1));
        uint4 out;
        if (row < M && col + 8 <= K) {
            const float* p = src + (size_t)row * K + col;
            float4 u0 = *reinterpret_cast<const float4*>(p);
            float4 u1 = *reinterpret_cast<const float4*>(p + 4);
            out.x = packbf2(u0.x, u0.y);
            out.y = packbf2(u0.z, u0.w);
            out.z = packbf2(u1.x, u1.y);
            out.w = packbf2(u1.z, u1.w);
        } else {
            unsigned short v[8];
            #pragma unroll
            for (int j = 0; j < 8; j++) {
                float f = 0.0f;
                if (row < M && col + j < K) f = src[(size_t)row * K + col + j];
                v[j] = f2bfbits(f);
            }
            out.x = ((unsigned)v[0]) | (((unsigned)v[1]) << 16);
            out.y = ((unsigned)v[2]) | (((unsigned)v[3]) << 16);
            out.z = ((unsigned)v[4]) | (((unsigned)v[5]) << 16);
            out.w = ((unsigned)v[6]) | (((unsigned)v[7]) << 16);
        }
        *reinterpret_cast<uint4*>(dst + o8) = out;
    }
}

__global__ __launch_bounds__(1024) void scan_conv_kernel(ScanConvArgs a) {
    int b = blockIdx.x;
    if (b < 2) {
        const unsigned* cnt; unsigned* row; int n;
        if (b == 0) { cnt = a.c0; row = a.r0; n = a.nA; }
        else        { cnt = a.c1; row = a.r1; n = a.nB; }
        __shared__ unsigned sdata[1024];
        __shared__ unsigned carry_s;
        int t = threadIdx.x;
        if (t == 0) carry_s = 0;
        __syncthreads();
        for (int base = 0; base < n; base += 1024) {
            int i = base + t;
            unsigned v = (i < n) ? cnt[i] : 0u;
            sdata[t] = v;
            __syncthreads();
            for (int off = 1; off < 1024; off <<= 1) {
                unsigned add = (t >= off) ? sdata[t - off] : 0u;
                __syncthreads();
                sdata[t] += add;
                __syncthreads();
            }
            unsigned incl = sdata[t];
            unsigned carry = carry_s;
            if (i < n) row[i] = carry + incl - v;
            __syncthreads();
            if (t == 1023) carry_s = carry + incl;
            __syncthreads();
        }
        if (t == 0) row[n] = carry_s;
    } else if (b < 2 + a.nConvA) {
        conv_body(a.fsrcA, a.fdstA, N_SAM, DSAM, MP_SAM, 11, b - 2, a.nConvA);
    } else if (b < 2 + a.nConvA + a.nConvB) {
        conv_body(a.fsrcB, a.fdstB, N_GEN, DGEN, MP_GEN, 9,
                  b - 2 - a.nConvA, a.nConvB);
    } else if (b < 2 + a.nConvA + a.nConvB + 8) {
        int zb = b - 2 - a.nConvA - a.nConvB;  // 0..7
        for (int i = zb * 1024 + threadIdx.x; i < a.nz0; i += 8 * 1024) a.z0[i] = 0;
        for (int i = zb * 1024 + threadIdx.x; i < a.nz1; i += 8 * 1024) a.z1[i] = 0;
    } else {
        int twb = b - (2 + a.nConvA + a.nConvB + 8);
        int d = 0;
        #pragma unroll
        for (int k = 1; k < 8; k++) if (twb >= a.twOff[k]) d = k;
        WDesc w = a.wd[d];
        int lb = twb - a.twOff[d];
        int nx = (w.N + 31) >> 5;
        int bx = lb % nx, by = lb / nx;
        int n  = bx * 32 + (threadIdx.x & 31);
        int kp = by * 32 + (threadIdx.x >> 5);
        if (n < w.N && kp < w.Kp) {
            float v = (kp < w.K) ? w.src[(size_t)kp * w.N + n] : 0.0f;
            w.dst[(size_t)n * w.Kp + kp] = f2bfbits(v);
        }
    }
}

// ---------------------------------------------------------------------------
// Per-(block,bin) starting cursors
// ---------------------------------------------------------------------------
__global__ __launch_bounds__(256) void cursor_kernel(
    const unsigned* __restrict__ cs_dsg, const unsigned* __restrict__ cs_dgs,
    const unsigned* __restrict__ row_sg, const unsigned* __restrict__ row_gs,
    unsigned* __restrict__ cur_sg_m, unsigned* __restrict__ cur_gs_m) {
    int i = blockIdx.x * 256 + threadIdx.x;
    const unsigned* cs; const unsigned* row; unsigned* cur; int nb;
    if (blockIdx.y == 0) { cs = cs_dsg; row = row_sg; cur = cur_sg_m; nb = 20000; }
    else                 { cs = cs_dgs; row = row_gs; cur = cur_gs_m; nb = 10000; }
    if (i >= nb) return;
    unsigned run = row[i];
    for (int b = 0; b < NB; b++) {
        cur[(size_t)b * nb + i] = run;
        run += cs[(size_t)b * nb + i];
    }
}

// ---------------------------------------------------------------------------
// Counting-sort phase 2: place edges with LDS cursors (no global atomics).
// ---------------------------------------------------------------------------
__global__ __launch_bounds__(1024) void scatter_sorted_kernel(
    const int* __restrict__ src_sg, const int* __restrict__ dst_sg,
    const int* __restrict__ src_gs, const int* __restrict__ dst_gs,
    const unsigned* __restrict__ cur_sg_m, const unsigned* __restrict__ cur_gs_m,
    int* __restrict__ col_sg, int* __restrict__ col_gs, int ne, int chunk) {
    __shared__ unsigned curs[SSPAN];
    int sl = blockIdx.y;
    const int* src; const int* dst; const unsigned* cmat; int* col; int lo, hi, nb;
    if (sl < 8) {
        src = src_sg; dst = dst_sg; cmat = cur_sg_m; col = col_sg; nb = 20000;
        lo = sl * SSPAN; hi = lo + SSPAN; if (hi > 20000) hi = 20000;
    } else {
        src = src_gs; dst = dst_gs; cmat = cur_gs_m; col = col_gs; nb = 10000;
        lo = (sl - 8) * SSPAN; hi = lo + SSPAN; if (hi > 10000) hi = 10000;
    }
    int span = hi - lo, blk = blockIdx.x;
    const unsigned* cin = cmat + (size_t)blk * nb + lo;
    for (int i = threadIdx.x; i < span; i += 1024) curs[i] = cin[i];
    __syncthreads();
    int e0 = blk * chunk;
    int e1 = e0 + chunk; if (e1 > ne) e1 = ne;
    for (int e = e0 + threadIdx.x; e < e1; e += 1024) {
        int d = dst[e];
        if (d >= lo && d < hi) {
            unsigned p = atomicAdd(&curs[d - lo], 1u);
            col[p] = src[e];
        }
    }
}

// ---------------------------------------------------------------------------
// MFMA bf16 GEMM, pipelined; TWO independent GEMMs fused per launch.
// Tile 64x64, 4 waves, BK=64, global_load_lds + double-buffer + XOR-swizzle.
// ---------------------------------------------------------------------------
struct GemmDesc {
    const unsigned short* A; const unsigned short* BT;
    const float* bias; const float* rs; unsigned short* C;
    int M, N, Kp, GX, GY;
};

__global__ __launch_bounds__(256) void gemm2_bf16(GemmDesc da, GemmDesc db, int nblkA) {
    int bi = blockIdx.x;
    GemmDesc d;
    if (bi < nblkA) { d = da; } else { d = db; bi -= nblkA; }
    int xcd = bi & 7, g = bi >> 3;
    int ntile = g % d.GX;
    int mtile = (g / d.GX) * 8 + xcd;
    if (mtile >= d.GY) return;
    int m0 = mtile * 64, n0 = ntile * 64;
    int Kp = d.Kp;

    __shared__ __attribute__((aligned(16))) unsigned short As[2][64 * 64];
    __shared__ __attribute__((aligned(16))) unsigned short Bs[2][64 * 64];

    int t = threadIdx.x;
    int lane = t & 63;
    int wave = t >> 6;
    int wm = (wave >> 1) * 32, wn = (wave & 1) * 32;
    int q = lane >> 4, mr = lane & 15;

    int r0 = t >> 3;
    int sw = ((t & 7) ^ (r0 & 7)) << 3;  // swizzled source column (ushorts)
    const unsigned short* a0 = d.A + (size_t)(m0 + r0) * Kp + sw;
    const unsigned short* b0 = d.BT + (size_t)(n0 + r0) * Kp + sw;
    const size_t rstep = (size_t)32 * Kp;
    unsigned short* asl0 = &As[0][t * 8];
    unsigned short* asl1 = &As[0][(256 + t) * 8];
    unsigned short* bsl0 = &Bs[0][t * 8];
    unsigned short* bsl1 = &Bs[0][(256 + t) * 8];
    const int bufoff = 64 * 64;

    f32x4 acc[2][2] = {};

    gload16(a0, asl0);
    gload16(a0 + rstep, asl1);
    gload16(b0, bsl0);
    gload16(b0 + rstep, bsl1);
    __syncthreads();

    int nt = Kp >> 6;
    for (int it = 0; it < nt; ++it) {
        int cur = it & 1;
        if (it + 1 < nt) {
            int k0 = (it + 1) << 6;
            int boff = (cur ^ 1) * bufoff;
            gload16(a0 + k0,         asl0 + boff);
            gload16(a0 + rstep + k0, asl1 + boff);
            gload16(b0 + k0,         bsl0 + boff);
            gload16(b0 + rstep + k0, bsl1 + boff);
        }
        #pragma unroll
        for (int kk = 0; kk < 64; kk += 32) {
            bf16x8 af[2], bfr[2];
            int cb = (kk >> 3) + q;
            #pragma unroll
            for (int i = 0; i < 2; i++) {
                int row = wm + i * 16 + mr;
                af[i] = *reinterpret_cast<const bf16x8*>(
                    &As[cur][row * 64 + ((cb ^ (row & 7)) << 3)]);
            }
            #pragma unroll
            for (int j = 0; j < 2; j++) {
                int row = wn + j * 16 + mr;
                bfr[j] = *reinterpret_cast<const bf16x8*>(
                    &Bs[cur][row * 64 + ((cb ^ (row & 7)) << 3)]);
            }
            #pragma unroll
            for (int i = 0; i < 2; i++)
                #pragma unroll
                for (int j = 0; j < 2; j++)
                    acc[i][j] = __builtin_amdgcn_mfma_f32_16x16x32_bf16(
                        af[i], bfr[j], acc[i][j], 0, 0, 0);
        }
        __syncthreads();
    }

    #pragma unroll
    for (int i = 0; i < 2; i++) {
        #pragma unroll
        for (int r = 0; r < 4; r++) {
            int row = m0 + wm + i * 16 + q * 4 + r;
            if (row >= d.M) continue;
            float sc = (d.rs != nullptr) ? d.rs[row] : 1.0f;
            #pragma unroll
            for (int j = 0; j < 2; j++) {
                int col = n0 + wn + j * 16 + mr;
                float v = acc[i][j][r];
                if (d.bias != nullptr) v += d.bias[col];
                v *= sc;
                d.C[(size_t)row * d.N + col] = f2bfbits(v);
            }
        }
    }
}

// ---------------------------------------------------------------------------
// XCD-affine CSR aggregation. Straight-line (no rotation — vmcnt is in-order,
// rotation can't help across the col->gather dependency). Col indices are
// re-partitioned CONTIGUOUSLY per lane-group so one int4 load feeds 4 edges;
// main loop batches 8 gathers per col-drain (half the stall frequency of the
// round-6 form, 2x outstanding L2 requests). Edge partition is commutative.
// ---------------------------------------------------------------------------
struct AggTask {
    const unsigned* rowptr; const int* col; const unsigned short* P;
    const float* rs_in; const float* bias; const float* rs_next;
    void* out;
    int row_begin; int row_end; int d0;
};
struct AggPack { AggTask t[8]; };

template <int D, int LPRS, bool OUTBF>
__device__ __forceinline__ void agg_body(const AggTask& t, int lblk, int nlb) {
    const int LPR = 1 << LPRS;        // lanes per row-slice (16 B each)
    const int NS  = 64 >> LPRS;       // edge sub-groups per wave
    int lane = threadIdx.x & 63;
    int wav  = threadIdx.x >> 6;
    int sub = lane >> LPRS;
    int li  = lane & (LPR - 1);
    const unsigned li8 = (unsigned)li * 8;
    const unsigned short* __restrict__ Pu = t.P + t.d0;   // uniform base
    const int* __restrict__ col = t.col;
    auto ld = [&](unsigned s) {
        return *reinterpret_cast<const uint4*>(Pu + (s * (unsigned)D + li8));
    };

    for (int r = t.row_begin + lblk * 4 + wav; r < t.row_end; r += nlb * 4) {
        unsigned e0 = t.rowptr[r], e1 = t.rowptr[r + 1];
        f32x2 ac0[4] = {}, ac1[4] = {};
        unsigned e = e0;
        // align e to 4 for int4 col loads (k <= 3 < NS edges, sub k handles one)
        unsigned k = (4u - (e & 3u)) & 3u;
        if (k) {
            if (k > e1 - e) k = e1 - e;
            if ((unsigned)sub < k) addu2(ld((unsigned)col[e + sub]), ac0);
            e += k;
        }
        // main: 8*NS edges/iter; sub handles col[e+sub*8 .. +7] (two int4 loads)
        for (; e + 8u * NS <= e1; e += 8u * NS) {
            const int4* cp = reinterpret_cast<const int4*>(&col[e + sub * 8]);
            int4 c0 = cp[0], c1 = cp[1];
            uint4 u0 = ld((unsigned)c0.x), u1 = ld((unsigned)c0.y);
            uint4 u2 = ld((unsigned)c0.z), u3 = ld((unsigned)c0.w);
            uint4 u4 = ld((unsigned)c1.x), u5 = ld((unsigned)c1.y);
            uint4 u6 = ld((unsigned)c1.z), u7 = ld((unsigned)c1.w);
            addu2(u0, ac0); addu2(u1, ac1); addu2(u2, ac0); addu2(u3, ac1);
            addu2(u4, ac0); addu2(u5, ac1); addu2(u6, ac0); addu2(u7, ac1);
        }
        // mid: 4*NS edges; sub handles col[e+sub*4 .. +3] (one int4 load)
        for (; e + 4u * NS <= e1; e += 4u * NS) {
            int4 c0 = *reinterpret_cast<const int4*>(&col[e + sub * 4]);
            uint4 u0 = ld((unsigned)c0.x), u1 = ld((unsigned)c0.y);
            uint4 u2 = ld((unsigned)c0.z), u3 = ld((unsigned)c0.w);
            addu2(u0, ac0); addu2(u1, ac1); addu2(u2, ac0); addu2(u3, ac1);
        }
        // tail: one edge per sub-group per step
        for (; e < e1; e += NS) {
            unsigned idx = e + sub;
            if (idx < e1) addu2(ld((unsigned)col[idx]), ac0);
        }
        float acf[8];
        #pragma unroll
        for (int j = 0; j < 4; j++) {
            f32x2 s = ac0[j] + ac1[j];
            acf[2 * j]     = s.x;
            acf[2 * j + 1] = s.y;
        }
        #pragma unroll
        for (int off = 32; off >= LPR; off >>= 1) {
            #pragma unroll
            for (int j = 0; j < 8; j++) acf[j] += __shfl_down(acf[j], off);
        }
        if (sub == 0) {
            float rsv = t.rs_in[r];
            float res[8];
            #pragma unroll
            for (int j = 0; j < 8; j++) {
                float v = acf[j] * rsv + t.bias[t.d0 + li * 8 + j];
                res[j] = (v >= 0.f) ? v : 0.25f * v;
            }
            if constexpr (OUTBF) {
                float sn = t.rs_next[r];
                uint4 o;
                o.x = packbf2(res[0] * sn, res[1] * sn);
                o.y = packbf2(res[2] * sn, res[3] * sn);
                o.z = packbf2(res[4] * sn, res[5] * sn);
                o.w = packbf2(res[6] * sn, res[7] * sn);
                *reinterpret_cast<uint4*>(
                    (unsigned short*)t.out + (size_t)r * D + t.d0 + li * 8) = o;
            } else {
                float* op = (float*)t.out + (size_t)r * D + t.d0 + li * 8;
                *reinterpret_cast<float4*>(op)     = make_float4(res[0], res[1], res[2], res[3]);
                *reinterpret_cast<float4*>(op + 4) = make_float4(res[4], res[5], res[6], res[7]);
            }
        }
    }
}

template <int DG, int LGS, int DS, int LSS, bool OUTBF>
__global__ __launch_bounds__(256) void agg_xcd_kernel(AggPack pk) {
    int task = blockIdx.x & 7;
    int lblk = blockIdx.x >> 3;
    int nlb  = (int)gridDim.x >> 3;
    if (task < 4) agg_body<DG, LGS, OUTBF>(pk.t[task], lblk, nlb);
    else          agg_body<DS, LSS, OUTBF>(pk.t[task], lblk, nlb);
}

// ---------------------------------------------------------------------------
// Launch
// ---------------------------------------------------------------------------
extern "C" void kernel_launch(void* const* d_in, const int* in_sizes, int n_in,
                              void* d_out, int out_size, void* d_ws, size_t ws_size,
                              hipStream_t stream) {
    const float* sam_feat = (const float*)d_in[0];
    const float* gen_feat = (const float*)d_in[1];
    const int* src_sg = (const int*)d_in[2];
    const int* dst_sg = (const int*)d_in[3];
    const int* src_gs = (const int*)d_in[4];
    const int* dst_gs = (const int*)d_in[5];
    const float* l1W = (const float*)d_in[6];
    const float* l1b = (const float*)d_in[7];
    const float* l2W = (const float*)d_in[8];
    const float* l2b = (const float*)d_in[9];
    const float* Wsg[3] = {(const float*)d_in[10], (const float*)d_in[14], (const float*)d_in[18]};
    const float* bsg[3] = {(const float*)d_in[11], (const float*)d_in[15], (const float*)d_in[19]};
    const float* Wgs[3] = {(const float*)d_in[12], (const float*)d_in[16], (const float*)d_in[20]};
    const float* bgs[3] = {(const float*)d_in[13], (const float*)d_in[17], (const float*)d_in[21]};
    const int NE = in_sizes[2];
    const int CHUNK = (NE + NB - 1) / NB;

    // ---- workspace carve ----
    char* base = (char*)d_ws;
    size_t off = 0;
    auto alloc = [&](size_t bytes) -> char* {
        char* p = base + off;
        off = (off + bytes + 255) & ~(size_t)255;
        return p;
    };
    unsigned* cs_ssg = (unsigned*)alloc((size_t)NB * N_SAM * 4);
    unsigned* cs_dsg = (unsigned*)alloc((size_t)NB * N_GEN * 4);
    unsigned* cs_sgs = (unsigned*)alloc((size_t)NB * N_GEN * 4);
    unsigned* cs_dgs = (unsigned*)alloc((size_t)NB * N_SAM * 4);
    unsigned* cnt_dsg = (unsigned*)alloc(N_GEN * 4);
    unsigned* cnt_dgs = (unsigned*)alloc(N_SAM * 4);
    unsigned* row_sg = (unsigned*)alloc((N_GEN + 1) * 4);
    unsigned* row_gs = (unsigned*)alloc((N_SAM + 1) * 4);
    unsigned* cur_sg_m = (unsigned*)alloc((size_t)NB * N_GEN * 4);
    unsigned* cur_gs_m = (unsigned*)alloc((size_t)NB * N_SAM * 4);
    float* rs_out_sam = (float*)alloc(N_SAM * 4);
    float* rs_in_sam  = (float*)alloc(N_SAM * 4);
    float* rs_out_gen = (float*)alloc(N_GEN * 4);
    float* rs_in_gen  = (float*)alloc(N_GEN * 4);
    int* col_sg = (int*)alloc((size_t)NE * 4);
    int* col_gs = (int*)alloc((size_t)NE * 4);
    unsigned short* hs = (unsigned short*)alloc((size_t)MP_SAM * 256 * 2);
    unsigned short* hg = (unsigned short*)alloc((size_t)MP_GEN * 256 * 2);
    unsigned short* ps = (unsigned short*)alloc((size_t)N_SAM * 256 * 2);
    unsigned short* pg = (unsigned short*)alloc((size_t)N_GEN * 256 * 2);
    const int KP1 = 2048, KP2 = 512;
    unsigned short* BT_l1 = (unsigned short*)alloc((size_t)256 * KP1 * 2);
    unsigned short* BT_l2 = (unsigned short*)alloc((size_t)256 * KP2 * 2);
    unsigned short* BT_sg[3], *BT_gs[3];
    const int LN[3] = {256, 128, 64};
    const int LK[3] = {256, 256, 128};
    for (int i = 0; i < 3; i++) {
        BT_sg[i] = (unsigned short*)alloc((size_t)LN[i] * LK[i] * 2);
        BT_gs[i] = (unsigned short*)alloc((size_t)LN[i] * LK[i] * 2);
    }
    unsigned short* A_sam = (unsigned short*)alloc((size_t)MP_SAM * KP1 * 2);  // 41.2 MB
    unsigned short* A_gen = (unsigned short*)alloc((size_t)MP_GEN * KP2 * 2);  // 20.5 MB
    (void)ws_size;

    // ---- graph preprocessing: atomic-free counting sort ----
    hist_count_kernel<<<dim3(NB, 6), 1024, 0, stream>>>(
        src_sg, dst_sg, src_gs, dst_gs, cs_ssg, cs_dsg, cs_sgs, cs_dgs, NE, CHUNK);
    reduce_counts_kernel<<<dim3((N_GEN + 255) / 256, 4), 256, 0, stream>>>(
        cs_ssg, cs_dsg, cs_sgs, cs_dgs, cnt_dsg, cnt_dgs,
        rs_out_sam, rs_in_gen, rs_out_gen, rs_in_sam);

    // fused: scans (2 blocks) + feature converts + pad zeroing + W transpose
    {
        ScanConvArgs a;
        a.c0 = cnt_dsg; a.r0 = row_sg; a.nA = N_GEN;
        a.c1 = cnt_dgs; a.r1 = row_gs; a.nB = N_SAM;
        a.fsrcA = sam_feat; a.fdstA = A_sam;
        a.fsrcB = gen_feat; a.fdstB = A_gen;
        a.z0 = hs + (size_t)N_SAM * 256; a.nz0 = (MP_SAM - N_SAM) * 256;
        a.z1 = hg + (size_t)N_GEN * 256; a.nz1 = (MP_GEN - N_GEN) * 256;
        a.nConvA = 1536; a.nConvB = 768;
        a.wd[0] = {l1W,    BT_l1,    DSAM, 256, KP1};
        a.wd[1] = {l2W,    BT_l2,    DGEN, 256, KP2};
        a.wd[2] = {Wsg[0], BT_sg[0], 256, 256, 256};
        a.wd[3] = {Wgs[0], BT_gs[0], 256, 256, 256};
        a.wd[4] = {Wsg[1], BT_sg[1], 256, 128, 256};
        a.wd[5] = {Wgs[1], BT_gs[1], 256, 128, 256};
        a.wd[6] = {Wsg[2], BT_sg[2], 128, 64, 128};
        a.wd[7] = {Wgs[2], BT_gs[2], 128, 64, 128};
        int run = 0;
        for (int i = 0; i < 8; i++) {
            a.twOff[i] = run;
            int nx = (a.wd[i].N + 31) >> 5, ny = (a.wd[i].Kp + 31) >> 5;
            run += nx * ny;
        }
        a.nTW = run;  // 848
        scan_conv_kernel<<<2 + 1536 + 768 + 8 + run, 1024, 0, stream>>>(a);
    }

    cursor_kernel<<<dim3((N_GEN + 255) / 256, 2), 256, 0, stream>>>(
        cs_dsg, cs_dgs, row_sg, row_gs, cur_sg_m, cur_gs_m);
    scatter_sorted_kernel<<<dim3(NB, 12), 1024, 0, stream>>>(
        src_sg, dst_sg, src_gs, dst_gs, cur_sg_m, cur_gs_m, col_sg, col_gs, NE, CHUNK);

    dim3 blk(256);
    const int GY_SAM = (N_SAM + 63) / 64;  // 157
    const int GY_GEN = (N_GEN + 63) / 64;  // 313
    auto swgrid = [](int GX, int GY) { return 8 * GX * ((GY + 7) / 8); };
    const int AGG_GRID = 2048;  // 256 block-slots per XCD task

    auto mkg = [](const unsigned short* A, const unsigned short* BT,
                  const float* bias, const float* rs, unsigned short* C,
                  int M, int N, int Kp, int GX, int GY) {
        GemmDesc d; d.A = A; d.BT = BT; d.bias = bias; d.rs = rs; d.C = C;
        d.M = M; d.N = N; d.Kp = Kp; d.GX = GX; d.GY = GY; return d;
    };
    auto mk = [](const unsigned* rp, const int* cl, const unsigned short* P,
                 const float* ri, const float* bi, const float* rn, void* out,
                 int rb, int re, int d0) {
        AggTask t; t.rowptr = rp; t.col = cl; t.P = P; t.rs_in = ri; t.bias = bi;
        t.rs_next = rn; t.out = out; t.row_begin = rb; t.row_end = re;
        t.d0 = d0; return t;
    };

    // ---- input projections (merged sam+gen, epilogue pre-scales by rs_out) ----
    {
        int nA = swgrid(4, GY_SAM), nB = swgrid(4, GY_GEN);
        gemm2_bf16<<<nA + nB, blk, 0, stream>>>(
            mkg(A_sam, BT_l1, l1b, rs_out_sam, hs, N_SAM, 256, KP1, 4, GY_SAM),
            mkg(A_gen, BT_l2, l2b, rs_out_gen, hg, N_GEN, 256, KP2, 4, GY_GEN), nA);
    }

    // ---- layer 1: 256 -> 256 ----
    {
        int nA = swgrid(4, GY_SAM), nB = swgrid(4, GY_GEN);
        gemm2_bf16<<<nA + nB, blk, 0, stream>>>(
            mkg(hs, BT_sg[0], nullptr, nullptr, ps, N_SAM, 256, 256, 4, GY_SAM),
            mkg(hg, BT_gs[0], nullptr, nullptr, pg, N_GEN, 256, 256, 4, GY_GEN), nA);
    }
    {
        AggPack p;
        p.t[0] = mk(row_sg, col_sg, ps, rs_in_gen, bsg[0], rs_out_gen, hg, 0, 10000,   0);
        p.t[1] = mk(row_sg, col_sg, ps, rs_in_gen, bsg[0], rs_out_gen, hg, 10000, 20000, 0);
        p.t[2] = mk(row_sg, col_sg, ps, rs_in_gen, bsg[0], rs_out_gen, hg, 0, 10000, 128);
        p.t[3] = mk(row_sg, col_sg, ps, rs_in_gen, bsg[0], rs_out_gen, hg, 10000, 20000, 128);
        p.t[4] = mk(row_gs, col_gs, pg, rs_in_sam, bgs[0], rs_out_sam, hs, 0, 10000,   0);
        p.t[5] = mk(row_gs, col_gs, pg, rs_in_sam, bgs[0], rs_out_sam, hs, 0, 10000,  64);
        p.t[6] = mk(row_gs, col_gs, pg, rs_in_sam, bgs[0], rs_out_sam, hs, 0, 10000, 128);
        p.t[7] = mk(row_gs, col_gs, pg, rs_in_sam, bgs[0], rs_out_sam, hs, 0, 10000, 192);
        agg_xcd_kernel<256, 4, 256, 3, true><<<AGG_GRID, blk, 0, stream>>>(p);
    }

    // ---- layer 2: 256 -> 128 ----
    {
        int nA = swgrid(2, GY_SAM), nB = swgrid(2, GY_GEN);
        gemm2_bf16<<<nA + nB, blk, 0, stream>>>(
            mkg(hs, BT_sg[1], nullptr, nullptr, ps, N_SAM, 128, 256, 2, GY_SAM),
            mkg(hg, BT_gs[1], nullptr, nullptr, pg, N_GEN, 128, 256, 2, GY_GEN), nA);
    }
    {
        AggPack p;
        p.t[0] = mk(row_sg, col_sg, ps, rs_in_gen, bsg[1], rs_out_gen, hg, 0, 5000, 0);
        p.t[1] = mk(row_sg, col_sg, ps, rs_in_gen, bsg[1], rs_out_gen, hg, 5000, 10000, 0);
        p.t[2] = mk(row_sg, col_sg, ps, rs_in_gen, bsg[1], rs_out_gen, hg, 10000, 15000, 0);
        p.t[3] = mk(row_sg, col_sg, ps, rs_in_gen, bsg[1], rs_out_gen, hg, 15000, 20000, 0);
        p.t[4] = mk(row_gs, col_gs, pg, rs_in_sam, bgs[1], rs_out_sam, hs, 0, 5000,  0);
        p.t[5] = mk(row_gs, col_gs, pg, rs_in_sam, bgs[1], rs_out_sam, hs, 5000, 10000, 0);
        p.t[6] = mk(row_gs, col_gs, pg, rs_in_sam, bgs[1], rs_out_sam, hs, 0, 5000, 64);
        p.t[7] = mk(row_gs, col_gs, pg, rs_in_sam, bgs[1], rs_out_sam, hs, 5000, 10000, 64);
        agg_xcd_kernel<128, 4, 128, 3, true><<<AGG_GRID, blk, 0, stream>>>(p);
    }

    // ---- layer 3: 128 -> 64, fp32 outputs straight into d_out ----
    {
        int nA = swgrid(1, GY_SAM), nB = swgrid(1, GY_GEN);
        gemm2_bf16<<<nA + nB, blk, 0, stream>>>(
            mkg(hs, BT_sg[2], nullptr, nullptr, ps, N_SAM, 64, 128, 1, GY_SAM),
            mkg(hg, BT_gs[2], nullptr, nullptr, pg, N_GEN, 64, 128, 1, GY_GEN), nA);
    }
    float* out_sam = (float*)d_out;
    float* out_gen = out_sam + (size_t)N_SAM * 64;
    {
        AggPack p;
        p.t[0] = mk(row_sg, col_sg, ps, rs_in_gen, bsg[2], nullptr, out_gen, 0, 5000, 0);
        p.t[1] = mk(row_sg, col_sg, ps, rs_in_gen, bsg[2], nullptr, out_gen, 5000, 10000, 0);
        p.t[2] = mk(row_sg, col_sg, ps, rs_in_gen, bsg[2], nullptr, out_gen, 10000, 15000, 0);
        p.t[3] = mk(row_sg, col_sg, ps, rs_in_gen, bsg[2], nullptr, out_gen, 15000, 20000, 0);
        p.t[4] = mk(row_gs, col_gs, pg, rs_in_sam, bgs[2], nullptr, out_sam, 0, 2500, 0);
        p.t[5] = mk(row_gs, col_gs, pg, rs_in_sam, bgs[2], nullptr, out_sam, 2500, 5000, 0);
        p.t[6] = mk(row_gs, col_gs, pg, rs_in_sam, bgs[2], nullptr, out_sam, 5000, 7500, 0);
        p.t[7] = mk(row_gs, col_gs, pg, rs_in_sam, bgs[2], nullptr, out_sam, 7500, 10000, 0);
        agg_xcd_kernel<64, 3, 64, 3, false><<<AGG_GRID, blk, 0, stream>>>(p);
    }
}

// Round 10
// 457.896 us; speedup vs baseline: 1.0754x; 1.0754x over previous
//
#include <hip/hip_runtime.h>
#include <hip/hip_bf16.h>
#include <stdint.h>

#define N_SAM 10000
#define N_GEN 20000
#define DSAM  2000
#define DGEN  500
#define NB    32      // counting-sort chunks (round-7 proven)
#define NBNS  10240   // max LDS bins per hist slice (40 KB)
#define SSPAN 2560    // scatter slice span (10 KB LDS, 12 slices -> 384 blocks)
#define MP_SAM 10048  // 157*64 padded rows
#define MP_GEN 20032  // 313*64 padded rows

typedef __hip_bfloat16 bf16;
typedef short bf16x8 __attribute__((ext_vector_type(8)));
typedef float f32x4 __attribute__((ext_vector_type(4)));
typedef float f32x2 __attribute__((ext_vector_type(2)));

__device__ __forceinline__ float bfbits2f(unsigned short u) {
    unsigned v = ((unsigned)u) << 16;
    return __builtin_bit_cast(float, v);
}
__device__ __forceinline__ unsigned short f2bfbits(float f) {
    bf16 h = __float2bfloat16(f);
    return __builtin_bit_cast(unsigned short, h);
}
__device__ __forceinline__ unsigned packbf2(float lo, float hi) {
    return ((unsigned)f2bfbits(lo)) | (((unsigned)f2bfbits(hi)) << 16);
}
// unpack one dword (2 bf16) -> float2
__device__ __forceinline__ f32x2 b2f2(unsigned x) {
    f32x2 r;
    r.x = __builtin_bit_cast(float, x << 16);
    r.y = __builtin_bit_cast(float, x & 0xffff0000u);
    return r;
}
__device__ __forceinline__ void addu2(uint4 u, f32x2* a) {
    a[0] += b2f2(u.x);
    a[1] += b2f2(u.y);
    a[2] += b2f2(u.z);
    a[3] += b2f2(u.w);
}
// async global->LDS 16B (dwordx4). LDS dest must be linear in lane order.
__device__ __forceinline__ void gload16(const unsigned short* g, unsigned short* l) {
    __builtin_amdgcn_global_load_lds(
        (const __attribute__((address_space(1))) void*)g,
        (__attribute__((address_space(3))) void*)l, 16, 0, 0);
}

// ---------------------------------------------------------------------------
// Counting-sort phase 1: per-(block,bin) histograms, LDS-privatized.
// ---------------------------------------------------------------------------
__global__ __launch_bounds__(1024) void hist_count_kernel(
    const int* __restrict__ ssg, const int* __restrict__ dsg,
    const int* __restrict__ sgs, const int* __restrict__ dgs,
    unsigned* __restrict__ cs_ssg, unsigned* __restrict__ cs_dsg,
    unsigned* __restrict__ cs_sgs, unsigned* __restrict__ cs_dgs,
    int ne, int chunk) {
    __shared__ unsigned bins[NBNS];
    const int* arr; unsigned* counts; int lo, hi, nb;
    switch (blockIdx.y) {
        case 0:  arr = ssg; counts = cs_ssg; lo = 0;     hi = 10000; nb = 10000; break;
        case 1:  arr = dsg; counts = cs_dsg; lo = 0;     hi = 10240; nb = 20000; break;
        case 2:  arr = dsg; counts = cs_dsg; lo = 10240; hi = 20000; nb = 20000; break;
        case 3:  arr = sgs; counts = cs_sgs; lo = 0;     hi = 10240; nb = 20000; break;
        case 4:  arr = sgs; counts = cs_sgs; lo = 10240; hi = 20000; nb = 20000; break;
        default: arr = dgs; counts = cs_dgs; lo = 0;     hi = 10000; nb = 10000; break;
    }
    int span = hi - lo;
    for (int i = threadIdx.x; i < span; i += 1024) bins[i] = 0u;
    __syncthreads();
    int blk = blockIdx.x;
    int e0 = blk * chunk;
    int e1 = e0 + chunk; if (e1 > ne) e1 = ne;
    for (int e = e0 + threadIdx.x; e < e1; e += 1024) {
        int b = arr[e];
        if (b >= lo && b < hi) atomicAdd(&bins[b - lo], 1u);
    }
    __syncthreads();
    unsigned* out = counts + (size_t)blk * nb + lo;
    for (int i = threadIdx.x; i < span; i += 1024) out[i] = bins[i];
}

// ---------------------------------------------------------------------------
// Reduce per-block counts -> totals; fused degree normalizers rsqrt(max(d,1)).
// ---------------------------------------------------------------------------
__global__ __launch_bounds__(256) void reduce_counts_kernel(
    const unsigned* __restrict__ cs_ssg, const unsigned* __restrict__ cs_dsg,
    const unsigned* __restrict__ cs_sgs, const unsigned* __restrict__ cs_dgs,
    unsigned* __restrict__ cnt_dsg, unsigned* __restrict__ cnt_dgs,
    float* __restrict__ rs_out_sam, float* __restrict__ rs_in_gen,
    float* __restrict__ rs_out_gen, float* __restrict__ rs_in_sam) {
    int i = blockIdx.x * 256 + threadIdx.x;
    int which = blockIdx.y;
    const unsigned* cs; int nb;
    switch (which) {
        case 0:  cs = cs_ssg; nb = 10000; break;
        case 1:  cs = cs_dsg; nb = 20000; break;
        case 2:  cs = cs_sgs; nb = 20000; break;
        default: cs = cs_dgs; nb = 10000; break;
    }
    if (i >= nb) return;
    unsigned s = 0;
    #pragma unroll 4
    for (int b = 0; b < NB; b++) s += cs[(size_t)b * nb + i];
    unsigned c = (s < 1u) ? 1u : s;
    float r = rsqrtf((float)c);
    if (which == 0)      { rs_out_sam[i] = r; }
    else if (which == 1) { cnt_dsg[i] = s; rs_in_gen[i] = r; }
    else if (which == 2) { rs_out_gen[i] = r; }
    else                 { cnt_dgs[i] = s; rs_in_sam[i] = r; }
}

// ---------------------------------------------------------------------------
// Weight transpose descriptor (used inside fused scan/conv kernel)
// ---------------------------------------------------------------------------
struct WDesc { const float* src; unsigned short* dst; int K, N, Kp; };

// ---------------------------------------------------------------------------
// Fused: two exclusive scans (blocks 0,1) + fp32->bf16 feature conversion +
// hs/hg pad zeroing + weight transpose (all independent of the scans).
// ---------------------------------------------------------------------------
struct ScanConvArgs {
    const unsigned* c0; unsigned* r0; int nA;
    const unsigned* c1; unsigned* r1; int nB;
    const float* fsrcA; unsigned short* fdstA;   // sam feats
    const float* fsrcB; unsigned short* fdstB;   // gen feats
    unsigned short* z0; int nz0; unsigned short* z1; int nz1;
    int nConvA, nConvB;  // block counts for the two convert ranges
    WDesc wd[8];
    int twOff[8];        // per-desc block prefix offsets
    int nTW;
};

__device__ __forceinline__ void conv_body(
    const float* __restrict__ src, unsigned short* __restrict__ dst,
    int M, int K, int Mp, int kshift, int cb, int ncb) {
    const int Kp = 1 << kshift;
    size_t ng = ((size_t)Mp << kshift) >> 3;  // groups of 8 elements
    for (size_t gi = (size_t)cb * 1024 + threadIdx.x; gi < ng;
         gi += (size_t)ncb * 1024) {
        size_t o8 = gi << 3;
        int row = (int)(o8 >> kshift);
        int col = (int)(o8 & (size_t)(Kp - 1));
        uint4 out;
        if (row < M && col + 8 <= K) {
            const float* p = src + (size_t)row * K + col;
            float4 u0 = *reinterpret_cast<const float4*>(p);
            float4 u1 = *reinterpret_cast<const float4*>(p + 4);
            out.x = packbf2(u0.x, u0.y);
            out.y = packbf2(u0.z, u0.w);
            out.z = packbf2(u1.x, u1.y);
            out.w = packbf2(u1.z, u1.w);
        } else {
            unsigned short v[8];
            #pragma unroll
            for (int j = 0; j < 8; j++) {
                float f = 0.0f;
                if (row < M && col + j < K) f = src[(size_t)row * K + col + j];
                v[j] = f2bfbits(f);
            }
            out.x = ((unsigned)v[0]) | (((unsigned)v[1]) << 16);
            out.y = ((unsigned)v[2]) | (((unsigned)v[3]) << 16);
            out.z = ((unsigned)v[4]) | (((unsigned)v[5]) << 16);
            out.w = ((unsigned)v[6]) | (((unsigned)v[7]) << 16);
        }
        *reinterpret_cast<uint4*>(dst + o8) = out;
    }
}

__global__ __launch_bounds__(1024) void scan_conv_kernel(ScanConvArgs a) {
    int b = blockIdx.x;
    if (b < 2) {
        const unsigned* cnt; unsigned* row; int n;
        if (b == 0) { cnt = a.c0; row = a.r0; n = a.nA; }
        else        { cnt = a.c1; row = a.r1; n = a.nB; }
        __shared__ unsigned sdata[1024];
        __shared__ unsigned carry_s;
        int t = threadIdx.x;
        if (t == 0) carry_s = 0;
        __syncthreads();
        for (int base = 0; base < n; base += 1024) {
            int i = base + t;
            unsigned v = (i < n) ? cnt[i] : 0u;
            sdata[t] = v;
            __syncthreads();
            for (int off = 1; off < 1024; off <<= 1) {
                unsigned add = (t >= off) ? sdata[t - off] : 0u;
                __syncthreads();
                sdata[t] += add;
                __syncthreads();
            }
            unsigned incl = sdata[t];
            unsigned carry = carry_s;
            if (i < n) row[i] = carry + incl - v;
            __syncthreads();
            if (t == 1023) carry_s = carry + incl;
            __syncthreads();
        }
        if (t == 0) row[n] = carry_s;
    } else if (b < 2 + a.nConvA) {
        conv_body(a.fsrcA, a.fdstA, N_SAM, DSAM, MP_SAM, 11, b - 2, a.nConvA);
    } else if (b < 2 + a.nConvA + a.nConvB) {
        conv_body(a.fsrcB, a.fdstB, N_GEN, DGEN, MP_GEN, 9,
                  b - 2 - a.nConvA, a.nConvB);
    } else if (b < 2 + a.nConvA + a.nConvB + 8) {
        int zb = b - 2 - a.nConvA - a.nConvB;  // 0..7
        for (int i = zb * 1024 + threadIdx.x; i < a.nz0; i += 8 * 1024) a.z0[i] = 0;
        for (int i = zb * 1024 + threadIdx.x; i < a.nz1; i += 8 * 1024) a.z1[i] = 0;
    } else {
        int twb = b - (2 + a.nConvA + a.nConvB + 8);
        int d = 0;
        #pragma unroll
        for (int k = 1; k < 8; k++) if (twb >= a.twOff[k]) d = k;
        WDesc w = a.wd[d];
        int lb = twb - a.twOff[d];
        int nx = (w.N + 31) >> 5;
        int bx = lb % nx, by = lb / nx;
        int n  = bx * 32 + (threadIdx.x & 31);
        int kp = by * 32 + (threadIdx.x >> 5);
        if (n < w.N && kp < w.Kp) {
            float v = (kp < w.K) ? w.src[(size_t)kp * w.N + n] : 0.0f;
            w.dst[(size_t)n * w.Kp + kp] = f2bfbits(v);
        }
    }
}

// ---------------------------------------------------------------------------
// Per-(block,bin) starting cursors
// ---------------------------------------------------------------------------
__global__ __launch_bounds__(256) void cursor_kernel(
    const unsigned* __restrict__ cs_dsg, const unsigned* __restrict__ cs_dgs,
    const unsigned* __restrict__ row_sg, const unsigned* __restrict__ row_gs,
    unsigned* __restrict__ cur_sg_m, unsigned* __restrict__ cur_gs_m) {
    int i = blockIdx.x * 256 + threadIdx.x;
    const unsigned* cs; const unsigned* row; unsigned* cur; int nb;
    if (blockIdx.y == 0) { cs = cs_dsg; row = row_sg; cur = cur_sg_m; nb = 20000; }
    else                 { cs = cs_dgs; row = row_gs; cur = cur_gs_m; nb = 10000; }
    if (i >= nb) return;
    unsigned run = row[i];
    for (int b = 0; b < NB; b++) {
        cur[(size_t)b * nb + i] = run;
        run += cs[(size_t)b * nb + i];
    }
}

// ---------------------------------------------------------------------------
// Counting-sort phase 2: place edges with LDS cursors (no global atomics).
// ---------------------------------------------------------------------------
__global__ __launch_bounds__(1024) void scatter_sorted_kernel(
    const int* __restrict__ src_sg, const int* __restrict__ dst_sg,
    const int* __restrict__ src_gs, const int* __restrict__ dst_gs,
    const unsigned* __restrict__ cur_sg_m, const unsigned* __restrict__ cur_gs_m,
    int* __restrict__ col_sg, int* __restrict__ col_gs, int ne, int chunk) {
    __shared__ unsigned curs[SSPAN];
    int sl = blockIdx.y;
    const int* src; const int* dst; const unsigned* cmat; int* col; int lo, hi, nb;
    if (sl < 8) {
        src = src_sg; dst = dst_sg; cmat = cur_sg_m; col = col_sg; nb = 20000;
        lo = sl * SSPAN; hi = lo + SSPAN; if (hi > 20000) hi = 20000;
    } else {
        src = src_gs; dst = dst_gs; cmat = cur_gs_m; col = col_gs; nb = 10000;
        lo = (sl - 8) * SSPAN; hi = lo + SSPAN; if (hi > 10000) hi = 10000;
    }
    int span = hi - lo, blk = blockIdx.x;
    const unsigned* cin = cmat + (size_t)blk * nb + lo;
    for (int i = threadIdx.x; i < span; i += 1024) curs[i] = cin[i];
    __syncthreads();
    int e0 = blk * chunk;
    int e1 = e0 + chunk; if (e1 > ne) e1 = ne;
    for (int e = e0 + threadIdx.x; e < e1; e += 1024) {
        int d = dst[e];
        if (d >= lo && d < hi) {
            unsigned p = atomicAdd(&curs[d - lo], 1u);
            col[p] = src[e];
        }
    }
}

// ---------------------------------------------------------------------------
// MFMA bf16 GEMM, pipelined; TWO independent GEMMs fused per launch.
// Tile 64x64, 4 waves, BK=64, global_load_lds + double-buffer + XOR-swizzle.
// ---------------------------------------------------------------------------
struct GemmDesc {
    const unsigned short* A; const unsigned short* BT;
    const float* bias; const float* rs; unsigned short* C;
    int M, N, Kp, GX, GY;
};

__global__ __launch_bounds__(256) void gemm2_bf16(GemmDesc da, GemmDesc db, int nblkA) {
    int bi = blockIdx.x;
    GemmDesc d;
    if (bi < nblkA) { d = da; } else { d = db; bi -= nblkA; }
    int xcd = bi & 7, g = bi >> 3;
    int ntile = g % d.GX;
    int mtile = (g / d.GX) * 8 + xcd;
    if (mtile >= d.GY) return;
    int m0 = mtile * 64, n0 = ntile * 64;
    int Kp = d.Kp;

    __shared__ __attribute__((aligned(16))) unsigned short As[2][64 * 64];
    __shared__ __attribute__((aligned(16))) unsigned short Bs[2][64 * 64];

    int t = threadIdx.x;
    int lane = t & 63;
    int wave = t >> 6;
    int wm = (wave >> 1) * 32, wn = (wave & 1) * 32;
    int q = lane >> 4, mr = lane & 15;

    int r0 = t >> 3;
    int sw = ((t & 7) ^ (r0 & 7)) << 3;  // swizzled source column (ushorts)
    const unsigned short* a0 = d.A + (size_t)(m0 + r0) * Kp + sw;
    const unsigned short* b0 = d.BT + (size_t)(n0 + r0) * Kp + sw;
    const size_t rstep = (size_t)32 * Kp;
    unsigned short* asl0 = &As[0][t * 8];
    unsigned short* asl1 = &As[0][(256 + t) * 8];
    unsigned short* bsl0 = &Bs[0][t * 8];
    unsigned short* bsl1 = &Bs[0][(256 + t) * 8];
    const int bufoff = 64 * 64;

    f32x4 acc[2][2] = {};

    gload16(a0, asl0);
    gload16(a0 + rstep, asl1);
    gload16(b0, bsl0);
    gload16(b0 + rstep, bsl1);
    __syncthreads();

    int nt = Kp >> 6;
    for (int it = 0; it < nt; ++it) {
        int cur = it & 1;
        if (it + 1 < nt) {
            int k0 = (it + 1) << 6;
            int boff = (cur ^ 1) * bufoff;
            gload16(a0 + k0,         asl0 + boff);
            gload16(a0 + rstep + k0, asl1 + boff);
            gload16(b0 + k0,         bsl0 + boff);
            gload16(b0 + rstep + k0, bsl1 + boff);
        }
        #pragma unroll
        for (int kk = 0; kk < 64; kk += 32) {
            bf16x8 af[2], bfr[2];
            int cb = (kk >> 3) + q;
            #pragma unroll
            for (int i = 0; i < 2; i++) {
                int row = wm + i * 16 + mr;
                af[i] = *reinterpret_cast<const bf16x8*>(
                    &As[cur][row * 64 + ((cb ^ (row & 7)) << 3)]);
            }
            #pragma unroll
            for (int j = 0; j < 2; j++) {
                int row = wn + j * 16 + mr;
                bfr[j] = *reinterpret_cast<const bf16x8*>(
                    &Bs[cur][row * 64 + ((cb ^ (row & 7)) << 3)]);
            }
            #pragma unroll
            for (int i = 0; i < 2; i++)
                #pragma unroll
                for (int j = 0; j < 2; j++)
                    acc[i][j] = __builtin_amdgcn_mfma_f32_16x16x32_bf16(
                        af[i], bfr[j], acc[i][j], 0, 0, 0);
        }
        __syncthreads();
    }

    #pragma unroll
    for (int i = 0; i < 2; i++) {
        #pragma unroll
        for (int r = 0; r < 4; r++) {
            int row = m0 + wm + i * 16 + q * 4 + r;
            if (row >= d.M) continue;
            float sc = (d.rs != nullptr) ? d.rs[row] : 1.0f;
            #pragma unroll
            for (int j = 0; j < 2; j++) {
                int col = n0 + wn + j * 16 + mr;
                float v = acc[i][j][r];
                if (d.bias != nullptr) v += d.bias[col];
                v *= sc;
                d.C[(size_t)row * d.N + col] = f2bfbits(v);
            }
        }
    }
}

// ---------------------------------------------------------------------------
// XCD-affine CSR aggregation — EXACT round-6 proven form (agg1 = 70.2 µs).
// Simple 4-deep interleaved-sub loop: the compiler software-pipelines this
// structure on its own; R7/R8 manual restructurings both regressed it.
// Compile-time (D, LPRS): shifts not muls, unrolled reduce, uniform P base.
// ---------------------------------------------------------------------------
struct AggTask {
    const unsigned* rowptr; const int* col; const unsigned short* P;
    const float* rs_in; const float* bias; const float* rs_next;
    void* out;
    int row_begin; int row_end; int d0;
};
struct AggPack { AggTask t[8]; };

template <int D, int LPRS, bool OUTBF>
__device__ __forceinline__ void agg_body(const AggTask& t, int lblk, int nlb) {
    const int LPR = 1 << LPRS;        // lanes per row-slice (16 B each)
    const int R   = 64 >> LPRS;       // edge slots per pass
    const int R4  = R * 4;
    int lane = threadIdx.x & 63;
    int wav  = threadIdx.x >> 6;
    int sub = lane >> LPRS;
    int li  = lane & (LPR - 1);
    const unsigned li8 = (unsigned)li * 8;
    const unsigned short* __restrict__ Pu = t.P + t.d0;   // uniform base
    const int* __restrict__ col = t.col;

    for (int r = t.row_begin + lblk * 4 + wav; r < t.row_end; r += nlb * 4) {
        unsigned e0 = t.rowptr[r], e1 = t.rowptr[r + 1];
        f32x2 ac0[4] = {}, ac1[4] = {};
        unsigned e = e0;
        for (; e + (unsigned)R4 <= e1; e += R4) {
            unsigned s0 = (unsigned)col[e + sub];
            unsigned s1 = (unsigned)col[e + R + sub];
            unsigned s2 = (unsigned)col[e + 2 * R + sub];
            unsigned s3 = (unsigned)col[e + 3 * R + sub];
            uint4 u0 = *reinterpret_cast<const uint4*>(Pu + (s0 * (unsigned)D + li8));
            uint4 u1 = *reinterpret_cast<const uint4*>(Pu + (s1 * (unsigned)D + li8));
            uint4 u2 = *reinterpret_cast<const uint4*>(Pu + (s2 * (unsigned)D + li8));
            uint4 u3 = *reinterpret_cast<const uint4*>(Pu + (s3 * (unsigned)D + li8));
            addu2(u0, ac0); addu2(u1, ac1); addu2(u2, ac0); addu2(u3, ac1);
        }
        for (; e < e1; e += R) {
            unsigned idx = e + sub;
            if (idx < e1) {
                unsigned s0 = (unsigned)col[idx];
                uint4 u = *reinterpret_cast<const uint4*>(Pu + (s0 * (unsigned)D + li8));
                addu2(u, ac0);
            }
        }
        float acf[8];
        #pragma unroll
        for (int j = 0; j < 4; j++) {
            f32x2 s = ac0[j] + ac1[j];
            acf[2 * j]     = s.x;
            acf[2 * j + 1] = s.y;
        }
        #pragma unroll
        for (int off = 32; off >= LPR; off >>= 1) {
            #pragma unroll
            for (int j = 0; j < 8; j++) acf[j] += __shfl_down(acf[j], off);
        }
        if (sub == 0) {
            float rsv = t.rs_in[r];
            float res[8];
            #pragma unroll
            for (int j = 0; j < 8; j++) {
                float v = acf[j] * rsv + t.bias[t.d0 + li * 8 + j];
                res[j] = (v >= 0.f) ? v : 0.25f * v;
            }
            if constexpr (OUTBF) {
                float sn = t.rs_next[r];
                uint4 o;
                o.x = packbf2(res[0] * sn, res[1] * sn);
                o.y = packbf2(res[2] * sn, res[3] * sn);
                o.z = packbf2(res[4] * sn, res[5] * sn);
                o.w = packbf2(res[6] * sn, res[7] * sn);
                *reinterpret_cast<uint4*>(
                    (unsigned short*)t.out + (size_t)r * D + t.d0 + li * 8) = o;
            } else {
                float* op = (float*)t.out + (size_t)r * D + t.d0 + li * 8;
                *reinterpret_cast<float4*>(op)     = make_float4(res[0], res[1], res[2], res[3]);
                *reinterpret_cast<float4*>(op + 4) = make_float4(res[4], res[5], res[6], res[7]);
            }
        }
    }
}

template <int DG, int LGS, int DS, int LSS, bool OUTBF>
__global__ __launch_bounds__(256) void agg_xcd_kernel(AggPack pk) {
    int task = blockIdx.x & 7;
    int lblk = blockIdx.x >> 3;
    int nlb  = (int)gridDim.x >> 3;
    if (task < 4) agg_body<DG, LGS, OUTBF>(pk.t[task], lblk, nlb);
    else          agg_body<DS, LSS, OUTBF>(pk.t[task], lblk, nlb);
}

// ---------------------------------------------------------------------------
// Launch
// ---------------------------------------------------------------------------
extern "C" void kernel_launch(void* const* d_in, const int* in_sizes, int n_in,
                              void* d_out, int out_size, void* d_ws, size_t ws_size,
                              hipStream_t stream) {
    const float* sam_feat = (const float*)d_in[0];
    const float* gen_feat = (const float*)d_in[1];
    const int* src_sg = (const int*)d_in[2];
    const int* dst_sg = (const int*)d_in[3];
    const int* src_gs = (const int*)d_in[4];
    const int* dst_gs = (const int*)d_in[5];
    const float* l1W = (const float*)d_in[6];
    const float* l1b = (const float*)d_in[7];
    const float* l2W = (const float*)d_in[8];
    const float* l2b = (const float*)d_in[9];
    const float* Wsg[3] = {(const float*)d_in[10], (const float*)d_in[14], (const float*)d_in[18]};
    const float* bsg[3] = {(const float*)d_in[11], (const float*)d_in[15], (const float*)d_in[19]};
    const float* Wgs[3] = {(const float*)d_in[12], (const float*)d_in[16], (const float*)d_in[20]};
    const float* bgs[3] = {(const float*)d_in[13], (const float*)d_in[17], (const float*)d_in[21]};
    const int NE = in_sizes[2];
    const int CHUNK = (NE + NB - 1) / NB;

    // ---- workspace carve ----
    char* base = (char*)d_ws;
    size_t off = 0;
    auto alloc = [&](size_t bytes) -> char* {
        char* p = base + off;
        off = (off + bytes + 255) & ~(size_t)255;
        return p;
    };
    unsigned* cs_ssg = (unsigned*)alloc((size_t)NB * N_SAM * 4);
    unsigned* cs_dsg = (unsigned*)alloc((size_t)NB * N_GEN * 4);
    unsigned* cs_sgs = (unsigned*)alloc((size_t)NB * N_GEN * 4);
    unsigned* cs_dgs = (unsigned*)alloc((size_t)NB * N_SAM * 4);
    unsigned* cnt_dsg = (unsigned*)alloc(N_GEN * 4);
    unsigned* cnt_dgs = (unsigned*)alloc(N_SAM * 4);
    unsigned* row_sg = (unsigned*)alloc((N_GEN + 1) * 4);
    unsigned* row_gs = (unsigned*)alloc((N_SAM + 1) * 4);
    unsigned* cur_sg_m = (unsigned*)alloc((size_t)NB * N_GEN * 4);
    unsigned* cur_gs_m = (unsigned*)alloc((size_t)NB * N_SAM * 4);
    float* rs_out_sam = (float*)alloc(N_SAM * 4);
    float* rs_in_sam  = (float*)alloc(N_SAM * 4);
    float* rs_out_gen = (float*)alloc(N_GEN * 4);
    float* rs_in_gen  = (float*)alloc(N_GEN * 4);
    int* col_sg = (int*)alloc((size_t)NE * 4);
    int* col_gs = (int*)alloc((size_t)NE * 4);
    unsigned short* hs = (unsigned short*)alloc((size_t)MP_SAM * 256 * 2);
    unsigned short* hg = (unsigned short*)alloc((size_t)MP_GEN * 256 * 2);
    unsigned short* ps = (unsigned short*)alloc((size_t)N_SAM * 256 * 2);
    unsigned short* pg = (unsigned short*)alloc((size_t)N_GEN * 256 * 2);
    const int KP1 = 2048, KP2 = 512;
    unsigned short* BT_l1 = (unsigned short*)alloc((size_t)256 * KP1 * 2);
    unsigned short* BT_l2 = (unsigned short*)alloc((size_t)256 * KP2 * 2);
    unsigned short* BT_sg[3], *BT_gs[3];
    const int LN[3] = {256, 128, 64};
    const int LK[3] = {256, 256, 128};
    for (int i = 0; i < 3; i++) {
        BT_sg[i] = (unsigned short*)alloc((size_t)LN[i] * LK[i] * 2);
        BT_gs[i] = (unsigned short*)alloc((size_t)LN[i] * LK[i] * 2);
    }
    unsigned short* A_sam = (unsigned short*)alloc((size_t)MP_SAM * KP1 * 2);  // 41.2 MB
    unsigned short* A_gen = (unsigned short*)alloc((size_t)MP_GEN * KP2 * 2);  // 20.5 MB
    (void)ws_size;

    // ---- graph preprocessing: atomic-free counting sort ----
    hist_count_kernel<<<dim3(NB, 6), 1024, 0, stream>>>(
        src_sg, dst_sg, src_gs, dst_gs, cs_ssg, cs_dsg, cs_sgs, cs_dgs, NE, CHUNK);
    reduce_counts_kernel<<<dim3((N_GEN + 255) / 256, 4), 256, 0, stream>>>(
        cs_ssg, cs_dsg, cs_sgs, cs_dgs, cnt_dsg, cnt_dgs,
        rs_out_sam, rs_in_gen, rs_out_gen, rs_in_sam);

    // fused: scans (2 blocks) + feature converts + pad zeroing + W transpose
    {
        ScanConvArgs a;
        a.c0 = cnt_dsg; a.r0 = row_sg; a.nA = N_GEN;
        a.c1 = cnt_dgs; a.r1 = row_gs; a.nB = N_SAM;
        a.fsrcA = sam_feat; a.fdstA = A_sam;
        a.fsrcB = gen_feat; a.fdstB = A_gen;
        a.z0 = hs + (size_t)N_SAM * 256; a.nz0 = (MP_SAM - N_SAM) * 256;
        a.z1 = hg + (size_t)N_GEN * 256; a.nz1 = (MP_GEN - N_GEN) * 256;
        a.nConvA = 1536; a.nConvB = 768;
        a.wd[0] = {l1W,    BT_l1,    DSAM, 256, KP1};
        a.wd[1] = {l2W,    BT_l2,    DGEN, 256, KP2};
        a.wd[2] = {Wsg[0], BT_sg[0], 256, 256, 256};
        a.wd[3] = {Wgs[0], BT_gs[0], 256, 256, 256};
        a.wd[4] = {Wsg[1], BT_sg[1], 256, 128, 256};
        a.wd[5] = {Wgs[1], BT_gs[1], 256, 128, 256};
        a.wd[6] = {Wsg[2], BT_sg[2], 128, 64, 128};
        a.wd[7] = {Wgs[2], BT_gs[2], 128, 64, 128};
        int run = 0;
        for (int i = 0; i < 8; i++) {
            a.twOff[i] = run;
            int nx = (a.wd[i].N + 31) >> 5, ny = (a.wd[i].Kp + 31) >> 5;
            run += nx * ny;
        }
        a.nTW = run;  // 848
        scan_conv_kernel<<<2 + 1536 + 768 + 8 + run, 1024, 0, stream>>>(a);
    }

    cursor_kernel<<<dim3((N_GEN + 255) / 256, 2), 256, 0, stream>>>(
        cs_dsg, cs_dgs, row_sg, row_gs, cur_sg_m, cur_gs_m);
    scatter_sorted_kernel<<<dim3(NB, 12), 1024, 0, stream>>>(
        src_sg, dst_sg, src_gs, dst_gs, cur_sg_m, cur_gs_m, col_sg, col_gs, NE, CHUNK);

    dim3 blk(256);
    const int GY_SAM = (N_SAM + 63) / 64;  // 157
    const int GY_GEN = (N_GEN + 63) / 64;  // 313
    auto swgrid = [](int GX, int GY) { return 8 * GX * ((GY + 7) / 8); };
    const int AGG_GRID = 2048;  // 256 block-slots per XCD task

    auto mkg = [](const unsigned short* A, const unsigned short* BT,
                  const float* bias, const float* rs, unsigned short* C,
                  int M, int N, int Kp, int GX, int GY) {
        GemmDesc d; d.A = A; d.BT = BT; d.bias = bias; d.rs = rs; d.C = C;
        d.M = M; d.N = N; d.Kp = Kp; d.GX = GX; d.GY = GY; return d;
    };
    auto mk = [](const unsigned* rp, const int* cl, const unsigned short* P,
                 const float* ri, const float* bi, const float* rn, void* out,
                 int rb, int re, int d0) {
        AggTask t; t.rowptr = rp; t.col = cl; t.P = P; t.rs_in = ri; t.bias = bi;
        t.rs_next = rn; t.out = out; t.row_begin = rb; t.row_end = re;
        t.d0 = d0; return t;
    };

    // ---- input projections (merged sam+gen, epilogue pre-scales by rs_out) ----
    {
        int nA = swgrid(4, GY_SAM), nB = swgrid(4, GY_GEN);
        gemm2_bf16<<<nA + nB, blk, 0, stream>>>(
            mkg(A_sam, BT_l1, l1b, rs_out_sam, hs, N_SAM, 256, KP1, 4, GY_SAM),
            mkg(A_gen, BT_l2, l2b, rs_out_gen, hg, N_GEN, 256, KP2, 4, GY_GEN), nA);
    }

    // ---- layer 1: 256 -> 256 ----
    {
        int nA = swgrid(4, GY_SAM), nB = swgrid(4, GY_GEN);
        gemm2_bf16<<<nA + nB, blk, 0, stream>>>(
            mkg(hs, BT_sg[0], nullptr, nullptr, ps, N_SAM, 256, 256, 4, GY_SAM),
            mkg(hg, BT_gs[0], nullptr, nullptr, pg, N_GEN, 256, 256, 4, GY_GEN), nA);
    }
    {
        AggPack p;
        p.t[0] = mk(row_sg, col_sg, ps, rs_in_gen, bsg[0], rs_out_gen, hg, 0, 10000,   0);
        p.t[1] = mk(row_sg, col_sg, ps, rs_in_gen, bsg[0], rs_out_gen, hg, 10000, 20000, 0);
        p.t[2] = mk(row_sg, col_sg, ps, rs_in_gen, bsg[0], rs_out_gen, hg, 0, 10000, 128);
        p.t[3] = mk(row_sg, col_sg, ps, rs_in_gen, bsg[0], rs_out_gen, hg, 10000, 20000, 128);
        p.t[4] = mk(row_gs, col_gs, pg, rs_in_sam, bgs[0], rs_out_sam, hs, 0, 10000,   0);
        p.t[5] = mk(row_gs, col_gs, pg, rs_in_sam, bgs[0], rs_out_sam, hs, 0, 10000,  64);
        p.t[6] = mk(row_gs, col_gs, pg, rs_in_sam, bgs[0], rs_out_sam, hs, 0, 10000, 128);
        p.t[7] = mk(row_gs, col_gs, pg, rs_in_sam, bgs[0], rs_out_sam, hs, 0, 10000, 192);
        agg_xcd_kernel<256, 4, 256, 3, true><<<AGG_GRID, blk, 0, stream>>>(p);
    }

    // ---- layer 2: 256 -> 128 ----
    {
        int nA = swgrid(2, GY_SAM), nB = swgrid(2, GY_GEN);
        gemm2_bf16<<<nA + nB, blk, 0, stream>>>(
            mkg(hs, BT_sg[1], nullptr, nullptr, ps, N_SAM, 128, 256, 2, GY_SAM),
            mkg(hg, BT_gs[1], nullptr, nullptr, pg, N_GEN, 128, 256, 2, GY_GEN), nA);
    }
    {
        AggPack p;
        p.t[0] = mk(row_sg, col_sg, ps, rs_in_gen, bsg[1], rs_out_gen, hg, 0, 5000, 0);
        p.t[1] = mk(row_sg, col_sg, ps, rs_in_gen, bsg[1], rs_out_gen, hg, 5000, 10000, 0);
        p.t[2] = mk(row_sg, col_sg, ps, rs_in_gen, bsg[1], rs_out_gen, hg, 10000, 15000, 0);
        p.t[3] = mk(row_sg, col_sg, ps, rs_in_gen, bsg[1], rs_out_gen, hg, 15000, 20000, 0);
        p.t[4] = mk(row_gs, col_gs, pg, rs_in_sam, bgs[1], rs_out_sam, hs, 0, 5000,  0);
        p.t[5] = mk(row_gs, col_gs, pg, rs_in_sam, bgs[1], rs_out_sam, hs, 5000, 10000, 0);
        p.t[6] = mk(row_gs, col_gs, pg, rs_in_sam, bgs[1], rs_out_sam, hs, 0, 5000, 64);
        p.t[7] = mk(row_gs, col_gs, pg, rs_in_sam, bgs[1], rs_out_sam, hs, 5000, 10000, 64);
        agg_xcd_kernel<128, 4, 128, 3, true><<<AGG_GRID, blk, 0, stream>>>(p);
    }

    // ---- layer 3: 128 -> 64, fp32 outputs straight into d_out ----
    {
        int nA = swgrid(1, GY_SAM), nB = swgrid(1, GY_GEN);
        gemm2_bf16<<<nA + nB, blk, 0, stream>>>(
            mkg(hs, BT_sg[2], nullptr, nullptr, ps, N_SAM, 64, 128, 1, GY_SAM),
            mkg(hg, BT_gs[2], nullptr, nullptr, pg, N_GEN, 64, 128, 1, GY_GEN), nA);
    }
    float* out_sam = (float*)d_out;
    float* out_gen = out_sam + (size_t)N_SAM * 64;
    {
        AggPack p;
        p.t[0] = mk(row_sg, col_sg, ps, rs_in_gen, bsg[2], nullptr, out_gen, 0, 5000, 0);
        p.t[1] = mk(row_sg, col_sg, ps, rs_in_gen, bsg[2], nullptr, out_gen, 5000, 10000, 0);
        p.t[2] = mk(row_sg, col_sg, ps, rs_in_gen, bsg[2], nullptr, out_gen, 10000, 15000, 0);
        p.t[3] = mk(row_sg, col_sg, ps, rs_in_gen, bsg[2], nullptr, out_gen, 15000, 20000, 0);
        p.t[4] = mk(row_gs, col_gs, pg, rs_in_sam, bgs[2], nullptr, out_sam, 0, 2500, 0);
        p.t[5] = mk(row_gs, col_gs, pg, rs_in_sam, bgs[2], nullptr, out_sam, 2500, 5000, 0);
        p.t[6] = mk(row_gs, col_gs, pg, rs_in_sam, bgs[2], nullptr, out_sam, 5000, 7500, 0);
        p.t[7] = mk(row_gs, col_gs, pg, rs_in_sam, bgs[2], nullptr, out_sam, 7500, 10000, 0);
        agg_xcd_kernel<64, 3, 64, 3, false><<<AGG_GRID, blk, 0, stream>>>(p);
    }
}